// Round 4
// baseline (264.766 us; speedup 1.0000x reference)
//
#include <hip/hip_runtime.h>

constexpr int kB  = 16;
constexpr int kLM = 1024;
constexpr int kLX = 1024;
constexpr int kD  = 768;

using short8 = __attribute__((ext_vector_type(8))) short;
using f32x4  = __attribute__((ext_vector_type(4))) float;

__device__ __forceinline__ unsigned short f2bf(float f) {
    unsigned u = __float_as_uint(f);
    u = (u + 0x7FFF + ((u >> 16) & 1)) >> 16;   // RNE
    return (unsigned short)u;
}
__device__ __forceinline__ float bf2f(unsigned short h) {
    return __uint_as_float(((unsigned)h) << 16);
}

// async 16B global->LDS copy; dst must be wave-uniform base + lane*16.
__device__ __forceinline__ void gl_lds16(const unsigned short* g, unsigned short* l) {
    auto gp = (const __attribute__((address_space(1))) unsigned int*)g;
    auto lp = (__attribute__((address_space(3))) unsigned int*)l;
    __builtin_amdgcn_global_load_lds(gp, lp, 16, 0, 0);
}

// ---------------------------------------------------------------------------
// Transpose + convert: xT[b][d][l] = bf16(x[b][l][d])
// ---------------------------------------------------------------------------
__global__ __launch_bounds__(256) void transpose_cvt_kernel(
    const float* __restrict__ x, unsigned short* __restrict__ xT) {
    __shared__ float tile[64][65];
    const int b  = blockIdx.z;
    const int l0 = blockIdx.x * 64;
    const int d0 = blockIdx.y * 64;
    const int t  = threadIdx.x;
    const int tx = t & 15, ty = t >> 4;
    const float* xb = x + ((size_t)b * kLX + l0) * kD + d0;
#pragma unroll
    for (int p = 0; p < 4; ++p) {
        int r = p * 16 + ty;
        float4 v = *(const float4*)(xb + (size_t)r * kD + tx * 4);
        *(float4*)&tile[r][tx * 4] = v;
    }
    __syncthreads();
    unsigned short* xTb = xT + ((size_t)b * kD + d0) * kLX + l0;
#pragma unroll
    for (int p = 0; p < 4; ++p) {
        int dr = p * 16 + ty;
        ushort4 o;
        o.x = f2bf(tile[tx * 4 + 0][dr]);
        o.y = f2bf(tile[tx * 4 + 1][dr]);
        o.z = f2bf(tile[tx * 4 + 2][dr]);
        o.w = f2bf(tile[tx * 4 + 3][dr]);
        *(ushort4*)(xTb + (size_t)dr * kLX + tx * 4) = o;
    }
}

// ---------------------------------------------------------------------------
// Fused fp32->bf16 convert for two tensors (main then W) in one dispatch.
// ---------------------------------------------------------------------------
__global__ __launch_bounds__(256) void cvt_bf16_dual_kernel(
    const float* __restrict__ a, unsigned short* __restrict__ oa, int n4a,
    const float* __restrict__ b, unsigned short* __restrict__ ob, int n4b) {
    int i = blockIdx.x * blockDim.x + threadIdx.x;
    const float* src; unsigned short* dst; int idx;
    if (i < n4a) { src = a; dst = oa; idx = i; }
    else { idx = i - n4a; if (idx >= n4b) return; src = b; dst = ob; }
    float4 v = ((const float4*)src)[idx];
    ushort4 o;
    o.x = f2bf(v.x); o.y = f2bf(v.y); o.z = f2bf(v.z); o.w = f2bf(v.w);
    ((ushort4*)dst)[idx] = o;
}

// ---------------------------------------------------------------------------
// NT bf16 MFMA GEMM, one-barrier double-buffered async pipeline.
// C[i][j] = sum_k A[i][k]*B[j][k]. 128x128 tile, BK=32, 256 thr (2x2 waves),
// 16x16x32 MFMA 4x4/wave. XOR-swizzled 16B-chunk LDS layout (R3, conflicts=0).
// Per iter: barrier (drains loads issued one compute-phase ago) -> issue
// prefetch(t+1) into other buffer -> ds_read+MFMA on tile t.
// ---------------------------------------------------------------------------
__global__ __launch_bounds__(256) void gemm_nt_bf16_kernel(
    const unsigned short* __restrict__ A, const unsigned short* __restrict__ B,
    unsigned short* __restrict__ C, int M, int N, int K,
    long sA, long sB, long sC) {
    __shared__ unsigned short Asm[2][128 * 32];   // 8 KB each
    __shared__ unsigned short Bsm[2][128 * 32];
    const int b  = blockIdx.z;
    const int i0 = blockIdx.x * 128;
    const int j0 = blockIdx.y * 128;
    const int t    = threadIdx.x;
    const int wave = t >> 6, lane = t & 63;
    const int wr = (wave >> 1) * 64, wc = (wave & 1) * 64;
    const int quad = lane >> 4, l15 = lane & 15;

    const unsigned short* Ab = A + (size_t)b * sA + (size_t)i0 * K;
    const unsigned short* Bb = B + (size_t)b * sB + (size_t)j0 * K;

    const int c0 = wave * 64 + lane;
    const int c1 = 256 + wave * 64 + lane;
    auto chunk_off = [&](int c) -> size_t {   // inverse swizzle chunk -> global
        int sr = c >> 3, s = c & 7;
        int tt = s ^ (sr & 7);
        int r  = sr * 2 + (tt >> 2);
        int q  = tt & 3;
        return (size_t)r * K + q * 8;
    };
    const size_t off0 = chunk_off(c0);
    const size_t off1 = chunk_off(c1);

    const int sfr = ((l15 & 1) * 4 + quad) ^ ((l15 >> 1) & 7);
    const int aOff = (wr >> 1) * 64 + (l15 >> 1) * 64 + sfr * 8;
    const int bOff = (wc >> 1) * 64 + (l15 >> 1) * 64 + sfr * 8;

    f32x4 acc[4][4];
    const f32x4 z = {0.f, 0.f, 0.f, 0.f};
#pragma unroll
    for (int i = 0; i < 4; ++i)
#pragma unroll
        for (int j = 0; j < 4; ++j) acc[i][j] = z;

    const int T = K >> 5;
    // prologue: tile 0 -> buf 0
    gl_lds16(Ab + off0, Asm[0] + c0 * 8);
    gl_lds16(Ab + off1, Asm[0] + c1 * 8);
    gl_lds16(Bb + off0, Bsm[0] + c0 * 8);
    gl_lds16(Bb + off1, Bsm[0] + c1 * 8);

    int buf = 0;
    for (int kt = 0; kt < T; ++kt) {
        __syncthreads();   // drains loads for tile kt (issued one phase ago)
        if (kt + 1 < T) {
            const size_t k = (size_t)(kt + 1) << 5;
            unsigned short* An = Asm[buf ^ 1];
            unsigned short* Bn = Bsm[buf ^ 1];
            gl_lds16(Ab + off0 + k, An + c0 * 8);
            gl_lds16(Ab + off1 + k, An + c1 * 8);
            gl_lds16(Bb + off0 + k, Bn + c0 * 8);
            gl_lds16(Bb + off1 + k, Bn + c1 * 8);
        }
        const unsigned short* aP = Asm[buf] + aOff;
        const unsigned short* bP = Bsm[buf] + bOff;
        short8 af[4], bg[4];
#pragma unroll
        for (int i = 0; i < 4; ++i) af[i] = *(const short8*)(aP + i * 512);
#pragma unroll
        for (int j = 0; j < 4; ++j) bg[j] = *(const short8*)(bP + j * 512);
#pragma unroll
        for (int i = 0; i < 4; ++i)
#pragma unroll
            for (int j = 0; j < 4; ++j)
                acc[i][j] = __builtin_amdgcn_mfma_f32_16x16x32_bf16(
                    af[i], bg[j], acc[i][j], 0, 0, 0);
        buf ^= 1;
    }

    // C/D layout: col = lane&15, row = quad*4 + reg  [m89/m91 verified]
    unsigned short* Cb = C + (size_t)b * sC + (size_t)(i0 + wr) * N + j0 + wc;
#pragma unroll
    for (int i = 0; i < 4; ++i)
#pragma unroll
        for (int j = 0; j < 4; ++j)
#pragma unroll
            for (int r = 0; r < 4; ++r)
                Cb[(size_t)(i * 16 + quad * 4 + r) * N + j * 16 + l15] =
                    f2bf(acc[i][j][r]);
}

// ---------------------------------------------------------------------------
// Fused beta + pooled. Grid (64,16): 4 blocks/CU. Wave handles 4 rows.
// ---------------------------------------------------------------------------
__global__ __launch_bounds__(256) void pool_kernel(
    const float* __restrict__ mainp, const unsigned short* __restrict__ Aout,
    const float* __restrict__ w, float* __restrict__ out) {
    const int b     = blockIdx.y;
    const int chunk = blockIdx.x;           // 64 chunks of 16 rows
    const int wave  = threadIdx.x >> 6, lane = threadIdx.x & 63;
    float w1[12], w2[12], ps[12], pm[12];
#pragma unroll
    for (int s = 0; s < 12; ++s) {
        w1[s] = w[s * 64 + lane];
        w2[s] = w[kD + s * 64 + lane];
        ps[s] = 0.f; pm[s] = 0.f;
    }
#pragma unroll
    for (int rr = 0; rr < 4; ++rr) {
        const int row = chunk * 16 + rr * 4 + wave;
        const float* mr = mainp + ((size_t)b * kLM + row) * kD;
        const unsigned short* ar = Aout + ((size_t)b * kLM + row) * kD;
        float sv[12], mv[12], acc = 0.f;
#pragma unroll
        for (int s = 0; s < 12; ++s) {
            float m_ = mr[s * 64 + lane];
            float a_ = bf2f(ar[s * 64 + lane]);
            sv[s] = m_ - a_;
            mv[s] = m_ * a_;
            acc += sv[s] * w1[s] + mv[s] * w2[s];
        }
#pragma unroll
        for (int off = 32; off; off >>= 1) acc += __shfl_xor(acc, off);
#pragma unroll
        for (int s = 0; s < 12; ++s) { ps[s] += acc * sv[s]; pm[s] += acc * mv[s]; }
    }
    float* ob = out + (size_t)b * 2 * kD;
#pragma unroll
    for (int s = 0; s < 12; ++s) {
        atomicAdd(&ob[s * 64 + lane], ps[s]);
        atomicAdd(&ob[kD + s * 64 + lane], pm[s]);
    }
}

extern "C" void kernel_launch(void* const* d_in, const int* in_sizes, int n_in,
                              void* d_out, int out_size, void* d_ws, size_t ws_size,
                              hipStream_t stream) {
    const float* mainp = (const float*)d_in[0];  // (B, LM, D)
    const float* x     = (const float*)d_in[1];  // (B, LX, D)
    const float* W     = (const float*)d_in[2];  // (D, D)
    const float* w     = (const float*)d_in[3];  // (2D, 1)
    float* out = (float*)d_out;                  // (B, 2D)

    char* p = (char*)d_ws;
    unsigned short* xT    = (unsigned short*)p; p += (size_t)kB * kD * kLX * 2;
    unsigned short* mainb = (unsigned short*)p; p += (size_t)kB * kLM * kD * 2;
    unsigned short* Wb    = (unsigned short*)p; p += (size_t)kD * kD * 2;
    unsigned short* G     = (unsigned short*)p; p += (size_t)kB * kD * kD * 2;
    unsigned short* Mt    = (unsigned short*)p; p += (size_t)kB * kD * kD * 2;
    unsigned short* Ao    = (unsigned short*)p; p += (size_t)kB * kLM * kD * 2;

    hipMemsetAsync(out, 0, (size_t)kB * 2 * kD * sizeof(float), stream);

    transpose_cvt_kernel<<<dim3(kLX / 64, kD / 64, kB), 256, 0, stream>>>(x, xT);
    {
        int n4a = kB * kLM * kD / 4;
        int n4b = kD * kD / 4;
        cvt_bf16_dual_kernel<<<(n4a + n4b + 255) / 256, 256, 0, stream>>>(
            mainp, mainb, n4a, W, Wb, n4b);
    }
    // G[b] = xT[b] @ xT[b]^T  (= x^T x, symmetric)
    gemm_nt_bf16_kernel<<<dim3(kD / 128, kD / 128, kB), 256, 0, stream>>>(
        xT, xT, G, kD, kD, kLX, (long)kD * kLX, (long)kD * kLX, (long)kD * kD);
    // Mt[b] = G[b] @ W^T   (= (W G)^T since G symmetric)
    gemm_nt_bf16_kernel<<<dim3(kD / 128, kD / 128, kB), 256, 0, stream>>>(
        G, Wb, Mt, kD, kD, kD, (long)kD * kD, 0L, (long)kD * kD);
    // A[b] = main[b] @ Mt[b]^T
    gemm_nt_bf16_kernel<<<dim3(kLM / 128, kD / 128, kB), 256, 0, stream>>>(
        mainb, Mt, Ao, kLM, kD, kD, (long)kLM * kD, (long)kD * kD, (long)kLM * kD);
    pool_kernel<<<dim3(kLM / 16, kB), 256, 0, stream>>>(mainp, Ao, w, out);
}